// Round 1
// baseline (323.119 us; speedup 1.0000x reference)
//
#include <hip/hip_runtime.h>
#include <math.h>

// Problem constants
#define Bsz 64
#define IC  512   // in_caps
#define KD  128   // in_dim
#define NC  32    // num_caps
#define DC  32    // dim_caps
#define CHUNK 64  // in_caps per block
#define NCH   8   // IC / CHUNK
#define NBLK  512 // Bsz * NCH
#define NTHR  256
#define GRPBLK 8  // blocks per b-group (barrier width)

#define CSTR 36   // padded stride for c_sT / wv_sT rows
#define BSTR 68   // padded stride for bb_s rows

// workspace layout (floats)
#define CXP_SZ (Bsz * NCH * NC * KD)   // 8 MB   cx partials [b][ch][n][k]
#define WV_SZ  (Bsz * NC * KD)         // 1 MB   wv [b][n][k]
#define NBAR 5

// x_s storage: row i holds k-quads rotated by (i>>2)
__device__ __forceinline__ int xaddr(int i, int kq) {
    return i * KD + ((((kq) + (i >> 2)) & 31) << 2);
}

// per-b-group barrier: 8 blocks of one b arrive; agent-scope fences for cxp/wv visibility
__device__ __forceinline__ void groupbar(unsigned* bar, int idx) {
    __syncthreads();
    if (threadIdx.x == 0) {
        __threadfence();   // release: drain/flush this block's global writes
        __hip_atomic_fetch_add(&bar[idx], 1u, __ATOMIC_RELEASE, __HIP_MEMORY_SCOPE_AGENT);
        while (__hip_atomic_load(&bar[idx], __ATOMIC_RELAXED, __HIP_MEMORY_SCOPE_AGENT) < GRPBLK) {
            __builtin_amdgcn_s_sleep(1);
        }
        __threadfence();   // acquire: invalidate stale cached lines
    }
    __syncthreads();
}

extern "C" __global__ __launch_bounds__(NTHR, 2)
void kFused(const float* __restrict__ x_g, const float* __restrict__ W_g,
            const float* __restrict__ b0_g, float* __restrict__ out_g,
            float* __restrict__ cxp, float* __restrict__ wv_g,
            unsigned* __restrict__ bar)
{
    __shared__ float x_s[CHUNK * KD];      // 32 KB, quad-rotated, persistent
    __shared__ float bb_s[NC * BSTR];      // 8.5 KB, persistent routing logits
    __shared__ float scr[KD * CSTR];       // 18 KB union: wv_sT / c_sT / (cxs+v)

    const int t = threadIdx.x, blk = blockIdx.x;
    // b = blk%64 so the 8 ch-blocks of a b share blk%8 -> same XCD (L2 locality heuristic)
    const int b = blk & 63, ch = blk >> 6, i0g = ch * CHUNK;

    // ---- stage x once (rotated) ----
    for (int rep = 0; rep < 8; ++rep) {
        int v = t + rep * NTHR;            // float4 idx 0..2047
        int i = v >> 5, kq = v & 31;
        *(float4*)(x_s + xaddr(i, kq)) =
            *(const float4*)(x_g + ((size_t)(b * IC + i0g + i)) * KD + (kq << 2));
    }
    // ---- stage bb once from b0; lives in LDS for all 3 iterations ----
    for (int rep = 0; rep < 2; ++rep) {
        int v = t + rep * NTHR;            // 0..511
        int n = v >> 4, i4 = v & 15;
        *(float4*)(bb_s + n * BSTR + (i4 << 2)) =
            *(const float4*)(b0_g + ((size_t)(b * NC + n)) * IC + i0g + (i4 << 2));
    }
    __syncthreads();

    int barIdx = 0;
    for (int it = 0; it < 3; ++it) {
        if (it > 0) {
            // stage wv transposed: [k][n] with CSTR pad
            for (int rep = 0; rep < 4; ++rep) {
                const int n = t & 31;
                const int k4 = (t >> 5) + (rep << 3);   // 0..31
                float4 v4 = *(const float4*)(wv_g + ((size_t)(b * NC) + n) * KD + (k4 << 2));
                scr[(k4 * 4 + 0) * CSTR + n] = v4.x;
                scr[(k4 * 4 + 1) * CSTR + n] = v4.y;
                scr[(k4 * 4 + 2) * CSTR + n] = v4.z;
                scr[(k4 * 4 + 3) * CSTR + n] = v4.w;
            }
            __syncthreads();
            // uv = wv @ X^T ; bb += uv. ALL 256 threads: kq range split in half,
            // the two halves combine via LDS float atomics (ds_add_f32).
            {
                const int tt = t & 127;
                const int tn = tt & 7, ti = tt >> 3;
                const int n0 = tn << 2, i0 = ti << 2;
                const int kq0 = (t >> 7) << 4;          // 0 or 16
                float4 a0 = {0,0,0,0}, a1 = {0,0,0,0}, a2 = {0,0,0,0}, a3 = {0,0,0,0};
                for (int kq = kq0; kq < kq0 + 16; ++kq) {
                    const float4 xr0 = *(const float4*)(x_s + xaddr(i0 + 0, kq));
                    const float4 xr1 = *(const float4*)(x_s + xaddr(i0 + 1, kq));
                    const float4 xr2 = *(const float4*)(x_s + xaddr(i0 + 2, kq));
                    const float4 xr3 = *(const float4*)(x_s + xaddr(i0 + 3, kq));
                    const float4 w0 = *(const float4*)(scr + (kq * 4 + 0) * CSTR + n0);
                    const float4 w1 = *(const float4*)(scr + (kq * 4 + 1) * CSTR + n0);
                    const float4 w2 = *(const float4*)(scr + (kq * 4 + 2) * CSTR + n0);
                    const float4 w3 = *(const float4*)(scr + (kq * 4 + 3) * CSTR + n0);
                    a0.x += xr0.x*w0.x + xr0.y*w1.x + xr0.z*w2.x + xr0.w*w3.x;
                    a0.y += xr0.x*w0.y + xr0.y*w1.y + xr0.z*w2.y + xr0.w*w3.y;
                    a0.z += xr0.x*w0.z + xr0.y*w1.z + xr0.z*w2.z + xr0.w*w3.z;
                    a0.w += xr0.x*w0.w + xr0.y*w1.w + xr0.z*w2.w + xr0.w*w3.w;
                    a1.x += xr1.x*w0.x + xr1.y*w1.x + xr1.z*w2.x + xr1.w*w3.x;
                    a1.y += xr1.x*w0.y + xr1.y*w1.y + xr1.z*w2.y + xr1.w*w3.y;
                    a1.z += xr1.x*w0.z + xr1.y*w1.z + xr1.z*w2.z + xr1.w*w3.z;
                    a1.w += xr1.x*w0.w + xr1.y*w1.w + xr1.z*w2.w + xr1.w*w3.w;
                    a2.x += xr2.x*w0.x + xr2.y*w1.x + xr2.z*w2.x + xr2.w*w3.x;
                    a2.y += xr2.x*w0.y + xr2.y*w1.y + xr2.z*w2.y + xr2.w*w3.y;
                    a2.z += xr2.x*w0.z + xr2.y*w1.z + xr2.z*w2.z + xr2.w*w3.z;
                    a2.w += xr2.x*w0.w + xr2.y*w1.w + xr2.z*w2.w + xr2.w*w3.w;
                    a3.x += xr3.x*w0.x + xr3.y*w1.x + xr3.z*w2.x + xr3.w*w3.x;
                    a3.y += xr3.x*w0.y + xr3.y*w1.y + xr3.z*w2.y + xr3.w*w3.y;
                    a3.z += xr3.x*w0.z + xr3.y*w1.z + xr3.z*w2.z + xr3.w*w3.z;
                    a3.w += xr3.x*w0.w + xr3.y*w1.w + xr3.z*w2.w + xr3.w*w3.w;
                }
                atomicAdd(&bb_s[(n0+0)*BSTR + i0+0], a0.x);
                atomicAdd(&bb_s[(n0+1)*BSTR + i0+0], a0.y);
                atomicAdd(&bb_s[(n0+2)*BSTR + i0+0], a0.z);
                atomicAdd(&bb_s[(n0+3)*BSTR + i0+0], a0.w);
                atomicAdd(&bb_s[(n0+0)*BSTR + i0+1], a1.x);
                atomicAdd(&bb_s[(n0+1)*BSTR + i0+1], a1.y);
                atomicAdd(&bb_s[(n0+2)*BSTR + i0+1], a1.z);
                atomicAdd(&bb_s[(n0+3)*BSTR + i0+1], a1.w);
                atomicAdd(&bb_s[(n0+0)*BSTR + i0+2], a2.x);
                atomicAdd(&bb_s[(n0+1)*BSTR + i0+2], a2.y);
                atomicAdd(&bb_s[(n0+2)*BSTR + i0+2], a2.z);
                atomicAdd(&bb_s[(n0+3)*BSTR + i0+2], a2.w);
                atomicAdd(&bb_s[(n0+0)*BSTR + i0+3], a3.x);
                atomicAdd(&bb_s[(n0+1)*BSTR + i0+3], a3.y);
                atomicAdd(&bb_s[(n0+2)*BSTR + i0+3], a3.z);
                atomicAdd(&bb_s[(n0+3)*BSTR + i0+3], a3.w);
            }
            __syncthreads();
        }

        // ---- softmax over n for each ii; write c^T into scr ----
        if (t < CHUNK) {
            const int ii = t;
            float m = -1e30f;
            #pragma unroll
            for (int n = 0; n < NC; ++n) m = fmaxf(m, bb_s[n * BSTR + ii]);
            float e[NC]; float sum = 0.f;
            #pragma unroll
            for (int n = 0; n < NC; ++n) { float ev = __expf(bb_s[n * BSTR + ii] - m); e[n] = ev; sum += ev; }
            const float inv = 1.f / sum;
            float* crow = scr + ii * CSTR;
            #pragma unroll
            for (int n = 0; n < NC; ++n) crow[n] = e[n] * inv;
        }
        __syncthreads();

        // ---- cx = C @ X (32n x 128k over 64 i); each thread 4n x 4k ----
        {
            const int tn = t & 7, tk = t >> 3;
            const int n0 = tn << 2;
            float4 acc0 = {0,0,0,0}, acc1 = {0,0,0,0}, acc2 = {0,0,0,0}, acc3 = {0,0,0,0};
            for (int ii = 0; ii < CHUNK; ++ii) {
                const float4 c4 = *(const float4*)(scr + ii * CSTR + n0);
                const float4 x4 = *(const float4*)(x_s + xaddr(ii, tk));
                acc0.x += c4.x*x4.x; acc0.y += c4.x*x4.y; acc0.z += c4.x*x4.z; acc0.w += c4.x*x4.w;
                acc1.x += c4.y*x4.x; acc1.y += c4.y*x4.y; acc1.z += c4.y*x4.z; acc1.w += c4.y*x4.w;
                acc2.x += c4.z*x4.x; acc2.y += c4.z*x4.y; acc2.z += c4.z*x4.z; acc2.w += c4.z*x4.w;
                acc3.x += c4.w*x4.x; acc3.y += c4.w*x4.y; acc3.z += c4.w*x4.z; acc3.w += c4.w*x4.w;
            }
            float* base = cxp + ((size_t)(b * NCH + ch)) * NC * KD + (tk << 2);
            *(float4*)(base + (size_t)(n0 + 0) * KD) = acc0;
            *(float4*)(base + (size_t)(n0 + 1) * KD) = acc1;
            *(float4*)(base + (size_t)(n0 + 2) * KD) = acc2;
            *(float4*)(base + (size_t)(n0 + 3) * KD) = acc3;
        }

        groupbar(bar, barIdx * Bsz + b); ++barIdx;   // all 8 ch-blocks of b wrote cxp

        // ---- B phase: wave w handles capsule n = ch*4+w for this b ----
        {
            const int w = t >> 6, l = t & 63;
            const int n = (ch << 2) + w;
            // 1) reduce cx partials over ch' (k = l and l+64), stage to LDS
            float c0 = 0.f, c1 = 0.f;
            const float* p = cxp + ((size_t)b * NCH * NC + n) * KD;
            #pragma unroll
            for (int c2 = 0; c2 < NCH; ++c2) {
                c0 += p[(size_t)c2 * NC * KD + l];
                c1 += p[(size_t)c2 * NC * KD + l + 64];
            }
            float* cxs = scr + w * KD;        // [4][128], overwrites c region (done)
            cxs[l] = c0; cxs[l + 64] = c1;
            __syncthreads();
            // 2) s[d] = sum_k cxs[k]*W[n][k][d]; lane = (dgrp=d/4, kg), k = j*8+kg
            const int dgrp = l & 7, d0 = dgrp << 2, kg = l >> 3;
            const float* Wn = W_g + (size_t)n * KD * DC;
            float4 acc = {0,0,0,0};
            #pragma unroll
            for (int j = 0; j < 16; ++j) {
                const int k = (j << 3) + kg;
                const float4 w4 = *(const float4*)(Wn + (size_t)k * DC + d0);
                const float cv = cxs[k];      // broadcast, conflict-free (8 addrs, distinct banks)
                acc.x += cv * w4.x; acc.y += cv * w4.y; acc.z += cv * w4.z; acc.w += cv * w4.w;
            }
            #pragma unroll
            for (int off = 8; off < 64; off <<= 1) {   // reduce over kg
                acc.x += __shfl_xor(acc.x, off, 64);
                acc.y += __shfl_xor(acc.y, off, 64);
                acc.z += __shfl_xor(acc.z, off, 64);
                acc.w += __shfl_xor(acc.w, off, 64);
            }
            // 3) squash: sn = sum_d s^2 (reduce over dgrp lanes)
            float ss = acc.x*acc.x + acc.y*acc.y + acc.z*acc.z + acc.w*acc.w;
            #pragma unroll
            for (int off = 1; off < 8; off <<= 1) ss += __shfl_xor(ss, off, 64);
            const float scale = ss / ((1.f + ss) * (sqrtf(ss) + 1e-8f));
            float4 v4; v4.x = acc.x*scale; v4.y = acc.y*scale; v4.z = acc.z*scale; v4.w = acc.w*scale;

            if (it == 2) {
                if (kg == 0) *(float4*)(out_g + ((size_t)(b * NC) + n) * DC + d0) = v4;
            } else {
                // 4) wv[n][k] = sum_d W[n][k][d]*v[d]; v staged per-wave in LDS
                float* vb = scr + 4 * KD + w * DC;
                if (kg == 0) *(float4*)(vb + d0) = v4;
                __threadfence_block();        // order LDS write->read within wave
                float wv0 = 0.f, wv1 = 0.f;
                #pragma unroll
                for (int j = 0; j < 8; ++j) {
                    const float4 vv = *(const float4*)(vb + (j << 2));           // broadcast
                    const float4 wa = *(const float4*)(Wn + (size_t)l * DC + (j << 2));
                    const float4 wb = *(const float4*)(Wn + (size_t)(l + 64) * DC + (j << 2));
                    wv0 += wa.x*vv.x + wa.y*vv.y + wa.z*vv.z + wa.w*vv.w;
                    wv1 += wb.x*vv.x + wb.y*vv.y + wb.z*vv.z + wb.w*vv.w;
                }
                float* wrow = wv_g + ((size_t)(b * NC) + n) * KD;
                wrow[l] = wv0; wrow[l + 64] = wv1;   // coalesced
            }
        }
        if (it < 2) { groupbar(bar, barIdx * Bsz + b); ++barIdx; }  // wv visible for next uv
    }
}

extern "C" void kernel_launch(void* const* d_in, const int* in_sizes, int n_in,
                              void* d_out, int out_size, void* d_ws, size_t ws_size,
                              hipStream_t stream) {
    const float* x  = (const float*)d_in[0];
    const float* W  = (const float*)d_in[1];
    const float* b0 = (const float*)d_in[2];
    float* out = (float*)d_out;

    float* cxp = (float*)d_ws;                   // 8 MB
    float* wv  = cxp + CXP_SZ;                   // 1 MB
    unsigned* bar = (unsigned*)(wv + WV_SZ);     // 5*64 counters

    hipMemsetAsync(bar, 0, NBAR * Bsz * sizeof(unsigned), stream);

    void* args[] = {(void*)&x, (void*)&W, (void*)&b0, (void*)&out,
                    (void*)&cxp, (void*)&wv, (void*)&bar};
    hipError_t err = hipLaunchCooperativeKernel((const void*)kFused, dim3(NBLK), dim3(NTHR),
                                                args, 0, stream);
    if (err != hipSuccess) {
        (void)hipGetLastError();
        // Fallback: plain launch. Co-residency is capacity-guaranteed:
        // 512 blocks, LDS 59.9KB -> 2 blocks/CU, VGPR capped by __launch_bounds__(256,2).
        hipLaunchKernelGGL(kFused, dim3(NBLK), dim3(NTHR), 0, stream,
                           x, W, b0, out, cxp, wv, bar);
    }
}

// Round 2
// 144.654 us; speedup vs baseline: 2.2337x; 2.2337x over previous
//
#include <hip/hip_runtime.h>
#include <math.h>

// Problem constants
#define Bsz 64
#define IC  512   // in_caps
#define KD  128   // in_dim
#define NC  32    // num_caps
#define DC  32    // dim_caps
#define CHUNK 64  // in_caps per block
#define NCH   8   // IC / CHUNK
#define NBLK  512 // Bsz * NCH
#define NTHR  256

#define CSTR 36   // padded stride for c_sT / wv_sT rows (floats)
#define BSTR 68   // padded stride for bb_s rows

// workspace layout (floats)
#define CXP_SZ (Bsz * NCH * NC * KD)   // 8 MB   cx partials [b][ch][n][k]
#define WV_SZ  (Bsz * NC * KD)         // 1 MB   wv [b][n][k]

// x_s storage: row i holds k-quads rotated by (i>>2): quad' = (quad + (i>>2)) & 31
__device__ __forceinline__ int xaddr(int i, int kq) {
    return i * KD + ((((kq) + (i >> 2)) & 31) << 2);
}

// ---------------- Kernel A: [uv + bb update] + softmax + cx partials ----------------
// block = (b, ch): blk&63 = b, blk>>6 = ch (b-major: the 8 ch-blocks of a b share blk%8
// -> same XCD under round-robin dispatch; perf heuristic only).
__global__ __launch_bounds__(NTHR, 2)
void kA(const float* __restrict__ bb_in, const float* __restrict__ x_g,
        const float* __restrict__ wv_g, float* __restrict__ bb_out,
        float* __restrict__ cxp, int do_uv, int write_bb)
{
    __shared__ float x_s[CHUNK * KD];      // 32 KB, quad-rotated
    __shared__ float bb_s[NC * BSTR];      // 8.5 KB
    __shared__ float scr[KD * CSTR];       // 18 KB union: wv_sT [k][n] then c_sT [i][n]

    const int t = threadIdx.x, blk = blockIdx.x;
    const int b = blk & 63, ch = blk >> 6, i0g = ch * CHUNK;

    // stage x (rotated)
    for (int rep = 0; rep < 8; ++rep) {
        int v = t + rep * NTHR;            // float4 idx 0..2047
        int i = v >> 5, kq = v & 31;
        *(float4*)(x_s + xaddr(i, kq)) =
            *(const float4*)(x_g + ((size_t)(b * IC + i0g + i)) * KD + (kq << 2));
    }
    // stage bb
    for (int rep = 0; rep < 2; ++rep) {
        int v = t + rep * NTHR;            // 0..511
        int n = v >> 4, i4 = v & 15;
        *(float4*)(bb_s + n * BSTR + (i4 << 2)) =
            *(const float4*)(bb_in + ((size_t)(b * NC + n)) * IC + i0g + (i4 << 2));
    }
    if (do_uv) {
        // stage wv transposed: [k][n] with CSTR pad
        for (int rep = 0; rep < 4; ++rep) {
            const int n = t & 31;
            const int k4 = (t >> 5) + (rep << 3);   // 0..31
            float4 v4 = *(const float4*)(wv_g + ((size_t)(b * NC) + n) * KD + (k4 << 2));
            scr[(k4 * 4 + 0) * CSTR + n] = v4.x;
            scr[(k4 * 4 + 1) * CSTR + n] = v4.y;
            scr[(k4 * 4 + 2) * CSTR + n] = v4.z;
            scr[(k4 * 4 + 3) * CSTR + n] = v4.w;
        }
    }
    __syncthreads();

    if (do_uv) {
        // uv = wv @ X^T ; bb += uv. ALL 256 threads: kq range split in half,
        // halves combined via LDS float atomics (ds_add).
        const int tt = t & 127;
        const int tn = tt & 7, ti = tt >> 3;
        const int n0 = tn << 2, i0 = ti << 2;
        const int kq0 = (t >> 7) << 4;          // 0 or 16
        float4 a0 = {0,0,0,0}, a1 = {0,0,0,0}, a2 = {0,0,0,0}, a3 = {0,0,0,0};
        for (int kq = kq0; kq < kq0 + 16; ++kq) {
            const float4 xr0 = *(const float4*)(x_s + xaddr(i0 + 0, kq));
            const float4 xr1 = *(const float4*)(x_s + xaddr(i0 + 1, kq));
            const float4 xr2 = *(const float4*)(x_s + xaddr(i0 + 2, kq));
            const float4 xr3 = *(const float4*)(x_s + xaddr(i0 + 3, kq));
            const float4 w0 = *(const float4*)(scr + (kq * 4 + 0) * CSTR + n0);
            const float4 w1 = *(const float4*)(scr + (kq * 4 + 1) * CSTR + n0);
            const float4 w2 = *(const float4*)(scr + (kq * 4 + 2) * CSTR + n0);
            const float4 w3 = *(const float4*)(scr + (kq * 4 + 3) * CSTR + n0);
            a0.x += xr0.x*w0.x + xr0.y*w1.x + xr0.z*w2.x + xr0.w*w3.x;
            a0.y += xr0.x*w0.y + xr0.y*w1.y + xr0.z*w2.y + xr0.w*w3.y;
            a0.z += xr0.x*w0.z + xr0.y*w1.z + xr0.z*w2.z + xr0.w*w3.z;
            a0.w += xr0.x*w0.w + xr0.y*w1.w + xr0.z*w2.w + xr0.w*w3.w;
            a1.x += xr1.x*w0.x + xr1.y*w1.x + xr1.z*w2.x + xr1.w*w3.x;
            a1.y += xr1.x*w0.y + xr1.y*w1.y + xr1.z*w2.y + xr1.w*w3.y;
            a1.z += xr1.x*w0.z + xr1.y*w1.z + xr1.z*w2.z + xr1.w*w3.z;
            a1.w += xr1.x*w0.w + xr1.y*w1.w + xr1.z*w2.w + xr1.w*w3.w;
            a2.x += xr2.x*w0.x + xr2.y*w1.x + xr2.z*w2.x + xr2.w*w3.x;
            a2.y += xr2.x*w0.y + xr2.y*w1.y + xr2.z*w2.y + xr2.w*w3.y;
            a2.z += xr2.x*w0.z + xr2.y*w1.z + xr2.z*w2.z + xr2.w*w3.z;
            a2.w += xr2.x*w0.w + xr2.y*w1.w + xr2.z*w2.w + xr2.w*w3.w;
            a3.x += xr3.x*w0.x + xr3.y*w1.x + xr3.z*w2.x + xr3.w*w3.x;
            a3.y += xr3.x*w0.y + xr3.y*w1.y + xr3.z*w2.y + xr3.w*w3.y;
            a3.z += xr3.x*w0.z + xr3.y*w1.z + xr3.z*w2.z + xr3.w*w3.z;
            a3.w += xr3.x*w0.w + xr3.y*w1.w + xr3.z*w2.w + xr3.w*w3.w;
        }
        atomicAdd(&bb_s[(n0+0)*BSTR + i0+0], a0.x);
        atomicAdd(&bb_s[(n0+1)*BSTR + i0+0], a0.y);
        atomicAdd(&bb_s[(n0+2)*BSTR + i0+0], a0.z);
        atomicAdd(&bb_s[(n0+3)*BSTR + i0+0], a0.w);
        atomicAdd(&bb_s[(n0+0)*BSTR + i0+1], a1.x);
        atomicAdd(&bb_s[(n0+1)*BSTR + i0+1], a1.y);
        atomicAdd(&bb_s[(n0+2)*BSTR + i0+1], a1.z);
        atomicAdd(&bb_s[(n0+3)*BSTR + i0+1], a1.w);
        atomicAdd(&bb_s[(n0+0)*BSTR + i0+2], a2.x);
        atomicAdd(&bb_s[(n0+1)*BSTR + i0+2], a2.y);
        atomicAdd(&bb_s[(n0+2)*BSTR + i0+2], a2.z);
        atomicAdd(&bb_s[(n0+3)*BSTR + i0+2], a2.w);
        atomicAdd(&bb_s[(n0+0)*BSTR + i0+3], a3.x);
        atomicAdd(&bb_s[(n0+1)*BSTR + i0+3], a3.y);
        atomicAdd(&bb_s[(n0+2)*BSTR + i0+3], a3.z);
        atomicAdd(&bb_s[(n0+3)*BSTR + i0+3], a3.w);
        __syncthreads();
        if (write_bb) {
            for (int rep = 0; rep < 2; ++rep) {
                int v = t + rep * NTHR;
                int n = v >> 4, i4 = v & 15;
                *(float4*)(bb_out + ((size_t)(b * NC + n)) * IC + i0g + (i4 << 2)) =
                    *(const float4*)(bb_s + n * BSTR + (i4 << 2));
            }
        }
    }

    // softmax over n for each ii; write c^T into scr
    if (t < CHUNK) {
        const int ii = t;
        float m = -1e30f;
        #pragma unroll
        for (int n = 0; n < NC; ++n) m = fmaxf(m, bb_s[n * BSTR + ii]);
        float e[NC]; float sum = 0.f;
        #pragma unroll
        for (int n = 0; n < NC; ++n) { float ev = __expf(bb_s[n * BSTR + ii] - m); e[n] = ev; sum += ev; }
        const float inv = 1.f / sum;
        float* crow = scr + ii * CSTR;
        #pragma unroll
        for (int n = 0; n < NC; ++n) crow[n] = e[n] * inv;
    }
    __syncthreads();

    // cx = C @ X (32n x 128k over 64 i); each thread 4n x 4k
    {
        const int tn = t & 7, tk = t >> 3;
        const int n0 = tn << 2;
        float4 acc0 = {0,0,0,0}, acc1 = {0,0,0,0}, acc2 = {0,0,0,0}, acc3 = {0,0,0,0};
        for (int ii = 0; ii < CHUNK; ++ii) {
            const float4 c4 = *(const float4*)(scr + ii * CSTR + n0);
            const float4 x4 = *(const float4*)(x_s + xaddr(ii, tk));
            acc0.x += c4.x*x4.x; acc0.y += c4.x*x4.y; acc0.z += c4.x*x4.z; acc0.w += c4.x*x4.w;
            acc1.x += c4.y*x4.x; acc1.y += c4.y*x4.y; acc1.z += c4.y*x4.z; acc1.w += c4.y*x4.w;
            acc2.x += c4.z*x4.x; acc2.y += c4.z*x4.y; acc2.z += c4.z*x4.z; acc2.w += c4.z*x4.w;
            acc3.x += c4.w*x4.x; acc3.y += c4.w*x4.y; acc3.z += c4.w*x4.z; acc3.w += c4.w*x4.w;
        }
        float* base = cxp + ((size_t)(b * NCH + ch)) * NC * KD + (tk << 2);
        *(float4*)(base + (size_t)(n0 + 0) * KD) = acc0;
        *(float4*)(base + (size_t)(n0 + 1) * KD) = acc1;
        *(float4*)(base + (size_t)(n0 + 2) * KD) = acc2;
        *(float4*)(base + (size_t)(n0 + 3) * KD) = acc3;
    }
}

// ---------------- Kernel B: reduce partials, s = cx@W[n], squash, wv or out ----------------
// block = (b, ngroup): blk&63 = b, blk>>6 = ng. Wave w handles capsule n = ng*4 + w.
// Lanes: kg = l>>3 (k split over 8 groups), dgrp = l&7 (d-quad). No serial 128-dot,
// no per-block W LDS staging: coalesced float4 W reads + shuffle reductions.
__global__ __launch_bounds__(NTHR, 2)
void kB(const float* __restrict__ cxp, const float* __restrict__ W_g,
        float* __restrict__ wv_g, float* __restrict__ out_g, int final_)
{
    __shared__ float cxs[4 * KD];          // per-wave reduced cx row
    __shared__ float vb[4 * DC];           // per-wave squashed v

    const int t = threadIdx.x, blk = blockIdx.x;
    const int b = blk & 63, ng = blk >> 6;
    const int w = t >> 6, l = t & 63;
    const int n = (ng << 2) + w;

    // 1) reduce cx partials over the 8 chunks (k = l and l+64), coalesced
    {
        float c0 = 0.f, c1 = 0.f;
        const float* p = cxp + ((size_t)b * NCH * NC + n) * KD;
        #pragma unroll
        for (int c2 = 0; c2 < NCH; ++c2) {
            c0 += p[(size_t)c2 * NC * KD + l];
            c1 += p[(size_t)c2 * NC * KD + l + 64];
        }
        cxs[w * KD + l] = c0; cxs[w * KD + l + 64] = c1;
    }
    __syncthreads();

    // 2) s[d0..d0+3] = sum_k cxs[k] * W[n][k][d]; k = j*8 + kg, 16 iters, full ILP
    const int dgrp = l & 7, d0 = dgrp << 2, kg = l >> 3;
    const float* Wn = W_g + (size_t)n * KD * DC;
    const float* cxw = cxs + w * KD;
    float4 acc = {0,0,0,0};
    #pragma unroll
    for (int j = 0; j < 16; ++j) {
        const int k = (j << 3) + kg;
        const float4 w4 = *(const float4*)(Wn + (size_t)k * DC + d0);
        const float cv = cxw[k];           // 8 distinct banks, broadcast within bank
        acc.x += cv * w4.x; acc.y += cv * w4.y; acc.z += cv * w4.z; acc.w += cv * w4.w;
    }
    #pragma unroll
    for (int off = 8; off < 64; off <<= 1) {   // reduce over kg lanes
        acc.x += __shfl_xor(acc.x, off, 64);
        acc.y += __shfl_xor(acc.y, off, 64);
        acc.z += __shfl_xor(acc.z, off, 64);
        acc.w += __shfl_xor(acc.w, off, 64);
    }
    // 3) squash: sn = sum_d s^2 (reduce over the 8 dgrp lanes)
    float ss = acc.x*acc.x + acc.y*acc.y + acc.z*acc.z + acc.w*acc.w;
    #pragma unroll
    for (int off = 1; off < 8; off <<= 1) ss += __shfl_xor(ss, off, 64);
    const float scale = ss / ((1.f + ss) * (sqrtf(ss) + 1e-8f));
    float4 v4; v4.x = acc.x*scale; v4.y = acc.y*scale; v4.z = acc.z*scale; v4.w = acc.w*scale;

    if (final_) {
        if (kg == 0) *(float4*)(out_g + ((size_t)(b * NC) + n) * DC + d0) = v4;
    } else {
        // 4) wv[n][k] = sum_d W[n][k][d] * v[d]; lane owns k = l and l+64
        float* vbw = vb + w * DC;
        if (kg == 0) *(float4*)(vbw + d0) = v4;
        __syncthreads();
        float wv0 = 0.f, wv1 = 0.f;
        #pragma unroll
        for (int j = 0; j < 8; ++j) {
            const float4 vv = *(const float4*)(vbw + (j << 2));              // broadcast
            const float4 wa = *(const float4*)(Wn + (size_t)l * DC + (j << 2));
            const float4 wb = *(const float4*)(Wn + (size_t)(l + 64) * DC + (j << 2));
            wv0 += wa.x*vv.x + wa.y*vv.y + wa.z*vv.z + wa.w*vv.w;
            wv1 += wb.x*vv.x + wb.y*vv.y + wb.z*vv.z + wb.w*vv.w;
        }
        float* wrow = wv_g + ((size_t)(b * NC) + n) * KD;
        wrow[l] = wv0; wrow[l + 64] = wv1;   // coalesced
    }
}

extern "C" void kernel_launch(void* const* d_in, const int* in_sizes, int n_in,
                              void* d_out, int out_size, void* d_ws, size_t ws_size,
                              hipStream_t stream) {
    const float* x  = (const float*)d_in[0];
    const float* W  = (const float*)d_in[1];
    const float* b0 = (const float*)d_in[2];
    float* out = (float*)d_out;

    float* cxp   = (float*)d_ws;                 // 8 MB
    float* wv    = cxp + CXP_SZ;                 // 1 MB
    float* bb_ws = wv + WV_SZ;                   // 4 MB

    // iter 0: softmax(b0) + cx
    kA<<<NBLK, NTHR, 0, stream>>>(b0, x, nullptr, nullptr, cxp, 0, 0);
    kB<<<NBLK, NTHR, 0, stream>>>(cxp, W, wv, nullptr, 0);
    // iter 1: uv+bb (persist) + softmax + cx
    kA<<<NBLK, NTHR, 0, stream>>>(b0, x, wv, bb_ws, cxp, 1, 1);
    kB<<<NBLK, NTHR, 0, stream>>>(cxp, W, wv, nullptr, 0);
    // iter 2: uv+bb + softmax + cx (bb not persisted)
    kA<<<NBLK, NTHR, 0, stream>>>(bb_ws, x, wv, nullptr, cxp, 1, 0);
    kB<<<NBLK, NTHR, 0, stream>>>(cxp, W, nullptr, out, 1);
}

// Round 3
// 128.012 us; speedup vs baseline: 2.5241x; 1.1300x over previous
//
#include <hip/hip_runtime.h>
#include <math.h>

// Problem constants
#define Bsz 64
#define IC  512   // in_caps
#define KD  128   // in_dim
#define NC  32    // num_caps
#define DC  32    // dim_caps
#define CHUNK 64  // in_caps per block
#define NCH   8   // IC / CHUNK
#define NBLK  512 // Bsz * NCH
#define NTHR  256

#define CSTR 36   // padded stride for c_sT / wv_sT rows (floats)
#define BSTR 68   // padded stride for bb_s rows
#define WSTR 33   // padded stride for w_s rows: bank=(k+d)%32 -> conflict-free col+row reads

// workspace layout (floats)
#define CXP_SZ (Bsz * NCH * NC * KD)   // 8 MB   cx partials [b][ch][n][k]
#define WV_SZ  (Bsz * NC * KD)         // 1 MB   wv [b][n][k]

// x_s storage: row i holds k-quads rotated by (i>>2): quad' = (quad + (i>>2)) & 31
__device__ __forceinline__ int xaddr(int i, int kq) {
    return i * KD + ((((kq) + (i >> 2)) & 31) << 2);
}

// ---------------- Kernel A: [uv + bb update] + softmax + cx partials ----------------
// Exactly the round-0 kACX (127.5 us verified): no min-waves cap, b = blk>>3.
__global__ __launch_bounds__(NTHR)
void kA(const float* __restrict__ bb_in, const float* __restrict__ x_g,
        const float* __restrict__ wv_g, float* __restrict__ bb_out,
        float* __restrict__ cxp, int do_uv, int write_bb)
{
    __shared__ float x_s[CHUNK * KD];      // 32 KB, quad-rotated
    __shared__ float bb_s[NC * BSTR];      // 8.5 KB
    __shared__ float scr[KD * CSTR];       // 18 KB union: wv_sT [k][n] then c_sT [i][n]

    const int t = threadIdx.x, blk = blockIdx.x;
    const int b = blk >> 3, ch = blk & 7, i0g = ch * CHUNK;

    // stage x (rotated)
    for (int rep = 0; rep < 8; ++rep) {
        int v = t + rep * NTHR;            // float4 idx 0..2047
        int i = v >> 5, kq = v & 31;
        *(float4*)(x_s + xaddr(i, kq)) =
            *(const float4*)(x_g + ((size_t)(b * IC + i0g + i)) * KD + (kq << 2));
    }
    // stage bb
    for (int rep = 0; rep < 2; ++rep) {
        int v = t + rep * NTHR;            // 0..511
        int n = v >> 4, i4 = v & 15;
        *(float4*)(bb_s + n * BSTR + (i4 << 2)) =
            *(const float4*)(bb_in + ((size_t)(b * NC + n)) * IC + i0g + (i4 << 2));
    }
    if (do_uv) {
        // stage wv transposed: [k][n] with CSTR pad
        for (int rep = 0; rep < 4; ++rep) {
            const int n = t & 31;
            const int k4 = (t >> 5) + (rep << 3);   // 0..31
            float4 v4 = *(const float4*)(wv_g + ((size_t)(b * NC) + n) * KD + (k4 << 2));
            scr[(k4 * 4 + 0) * CSTR + n] = v4.x;
            scr[(k4 * 4 + 1) * CSTR + n] = v4.y;
            scr[(k4 * 4 + 2) * CSTR + n] = v4.z;
            scr[(k4 * 4 + 3) * CSTR + n] = v4.w;
        }
    }
    __syncthreads();

    if (do_uv) {
        // uv = wv @ X^T ; bb += uv   (t<128: 4n x 4i tile each)
        if (t < 128) {
            const int tn = t & 7, ti = t >> 3;
            const int n0 = tn << 2, i0 = ti << 2;
            float4 a0 = {0,0,0,0}, a1 = {0,0,0,0}, a2 = {0,0,0,0}, a3 = {0,0,0,0};
            for (int kq = 0; kq < 32; ++kq) {
                const float4 xr0 = *(const float4*)(x_s + xaddr(i0 + 0, kq));
                const float4 xr1 = *(const float4*)(x_s + xaddr(i0 + 1, kq));
                const float4 xr2 = *(const float4*)(x_s + xaddr(i0 + 2, kq));
                const float4 xr3 = *(const float4*)(x_s + xaddr(i0 + 3, kq));
                const float4 w0 = *(const float4*)(scr + (kq * 4 + 0) * CSTR + n0);
                const float4 w1 = *(const float4*)(scr + (kq * 4 + 1) * CSTR + n0);
                const float4 w2 = *(const float4*)(scr + (kq * 4 + 2) * CSTR + n0);
                const float4 w3 = *(const float4*)(scr + (kq * 4 + 3) * CSTR + n0);
                a0.x += xr0.x*w0.x + xr0.y*w1.x + xr0.z*w2.x + xr0.w*w3.x;
                a0.y += xr0.x*w0.y + xr0.y*w1.y + xr0.z*w2.y + xr0.w*w3.y;
                a0.z += xr0.x*w0.z + xr0.y*w1.z + xr0.z*w2.z + xr0.w*w3.z;
                a0.w += xr0.x*w0.w + xr0.y*w1.w + xr0.z*w2.w + xr0.w*w3.w;
                a1.x += xr1.x*w0.x + xr1.y*w1.x + xr1.z*w2.x + xr1.w*w3.x;
                a1.y += xr1.x*w0.y + xr1.y*w1.y + xr1.z*w2.y + xr1.w*w3.y;
                a1.z += xr1.x*w0.z + xr1.y*w1.z + xr1.z*w2.z + xr1.w*w3.z;
                a1.w += xr1.x*w0.w + xr1.y*w1.w + xr1.z*w2.w + xr1.w*w3.w;
                a2.x += xr2.x*w0.x + xr2.y*w1.x + xr2.z*w2.x + xr2.w*w3.x;
                a2.y += xr2.x*w0.y + xr2.y*w1.y + xr2.z*w2.y + xr2.w*w3.y;
                a2.z += xr2.x*w0.z + xr2.y*w1.z + xr2.z*w2.z + xr2.w*w3.z;
                a2.w += xr2.x*w0.w + xr2.y*w1.w + xr2.z*w2.w + xr2.w*w3.w;
                a3.x += xr3.x*w0.x + xr3.y*w1.x + xr3.z*w2.x + xr3.w*w3.x;
                a3.y += xr3.x*w0.y + xr3.y*w1.y + xr3.z*w2.y + xr3.w*w3.y;
                a3.z += xr3.x*w0.z + xr3.y*w1.z + xr3.z*w2.z + xr3.w*w3.z;
                a3.w += xr3.x*w0.w + xr3.y*w1.w + xr3.z*w2.w + xr3.w*w3.w;
            }
            bb_s[(n0+0)*BSTR + i0+0] += a0.x; bb_s[(n0+1)*BSTR + i0+0] += a0.y;
            bb_s[(n0+2)*BSTR + i0+0] += a0.z; bb_s[(n0+3)*BSTR + i0+0] += a0.w;
            bb_s[(n0+0)*BSTR + i0+1] += a1.x; bb_s[(n0+1)*BSTR + i0+1] += a1.y;
            bb_s[(n0+2)*BSTR + i0+1] += a1.z; bb_s[(n0+3)*BSTR + i0+1] += a1.w;
            bb_s[(n0+0)*BSTR + i0+2] += a2.x; bb_s[(n0+1)*BSTR + i0+2] += a2.y;
            bb_s[(n0+2)*BSTR + i0+2] += a2.z; bb_s[(n0+3)*BSTR + i0+2] += a2.w;
            bb_s[(n0+0)*BSTR + i0+3] += a3.x; bb_s[(n0+1)*BSTR + i0+3] += a3.y;
            bb_s[(n0+2)*BSTR + i0+3] += a3.z; bb_s[(n0+3)*BSTR + i0+3] += a3.w;
        }
        __syncthreads();
        if (write_bb) {
            for (int rep = 0; rep < 2; ++rep) {
                int v = t + rep * NTHR;
                int n = v >> 4, i4 = v & 15;
                *(float4*)(bb_out + ((size_t)(b * NC + n)) * IC + i0g + (i4 << 2)) =
                    *(const float4*)(bb_s + n * BSTR + (i4 << 2));
            }
        }
    }

    // softmax over n for each ii; write c^T into scr
    if (t < CHUNK) {
        const int ii = t;
        float m = -1e30f;
        #pragma unroll
        for (int n = 0; n < NC; ++n) m = fmaxf(m, bb_s[n * BSTR + ii]);
        float e[NC]; float sum = 0.f;
        #pragma unroll
        for (int n = 0; n < NC; ++n) { float ev = __expf(bb_s[n * BSTR + ii] - m); e[n] = ev; sum += ev; }
        const float inv = 1.f / sum;
        float* crow = scr + ii * CSTR;
        #pragma unroll
        for (int n = 0; n < NC; ++n) crow[n] = e[n] * inv;
    }
    __syncthreads();

    // cx = C @ X (32n x 128k over 64 i); each thread 4n x 4k
    {
        const int tn = t & 7, tk = t >> 3;
        const int n0 = tn << 2;
        float4 acc0 = {0,0,0,0}, acc1 = {0,0,0,0}, acc2 = {0,0,0,0}, acc3 = {0,0,0,0};
        for (int ii = 0; ii < CHUNK; ++ii) {
            const float4 c4 = *(const float4*)(scr + ii * CSTR + n0);
            const float4 x4 = *(const float4*)(x_s + xaddr(ii, tk));
            acc0.x += c4.x*x4.x; acc0.y += c4.x*x4.y; acc0.z += c4.x*x4.z; acc0.w += c4.x*x4.w;
            acc1.x += c4.y*x4.x; acc1.y += c4.y*x4.y; acc1.z += c4.y*x4.z; acc1.w += c4.y*x4.w;
            acc2.x += c4.z*x4.x; acc2.y += c4.z*x4.y; acc2.z += c4.z*x4.z; acc2.w += c4.z*x4.w;
            acc3.x += c4.w*x4.x; acc3.y += c4.w*x4.y; acc3.z += c4.w*x4.z; acc3.w += c4.w*x4.w;
        }
        float* base = cxp + ((size_t)(b * NCH + ch)) * NC * KD + (tk << 2);
        *(float4*)(base + (size_t)(n0 + 0) * KD) = acc0;
        *(float4*)(base + (size_t)(n0 + 1) * KD) = acc1;
        *(float4*)(base + (size_t)(n0 + 2) * KD) = acc2;
        *(float4*)(base + (size_t)(n0 + 3) * KD) = acc3;
    }
}

// ---------------- Kernel B: reduce partials, s = cx@W[n], squash, wv or out ----------------
// block = (group-of-4 b, n): pb_n = blk&31, pb_b0 = (blk>>5)*4. 256 threads = 4 waves;
// wave w handles b = pb_b0 + w. W[n] staged ONCE to LDS (16.5 KB), shared by all 4 waves.
// Per-wave dot: lane = (kg = l>>3, dgrp = l&7); k = j*8+kg (16 iters, float4 ILP);
// shuffle reduce over kg, then squash-reduce over dgrp. No serial 128-dot anywhere.
__global__ __launch_bounds__(NTHR)
void kB(const float* __restrict__ cxp, const float* __restrict__ W_g,
        float* __restrict__ wv_g, float* __restrict__ out_g, int final_)
{
    __shared__ float w_s[KD * WSTR];       // 16.5 KB, padded [k][d], bank=(k+d)%32
    __shared__ float cxs[4 * KD];          // 2 KB: per-wave reduced cx row
    __shared__ float vb[4 * DC];           // 512 B: per-wave squashed v

    const int t = threadIdx.x, blk = blockIdx.x;
    const int pb_n = blk & 31, pb_b0 = (blk >> 5) * 4;
    const int w = t >> 6, l = t & 63;
    const int b = pb_b0 + w;

    // stage W[n] with row pad 33 (float4 load, 4 scalar stores; <=2-way banks = free)
    for (int rep = 0; rep < 4; ++rep) {
        int v = t + rep * NTHR;            // 0..1023 float4s
        int k = v >> 3, d0 = (v & 7) << 2;
        float4 w4 = *(const float4*)(W_g + (size_t)pb_n * KD * DC + ((size_t)v << 2));
        float* dst = w_s + k * WSTR + d0;
        dst[0] = w4.x; dst[1] = w4.y; dst[2] = w4.z; dst[3] = w4.w;
    }
    // 1) reduce cx partials over the 8 chunks: wave w owns b, lane owns k = l, l+64
    {
        float c0 = 0.f, c1 = 0.f;
        const float* p = cxp + ((size_t)b * NCH * NC + pb_n) * KD;
        #pragma unroll
        for (int c2 = 0; c2 < NCH; ++c2) {
            c0 += p[(size_t)c2 * NC * KD + l];
            c1 += p[(size_t)c2 * NC * KD + l + 64];
        }
        cxs[w * KD + l] = c0; cxs[w * KD + l + 64] = c1;
    }
    __syncthreads();

    // 2) s[d0..d0+3] = sum_k cx[k] * W[k][d]; k = j*8 + kg
    const int dgrp = l & 7, d0 = dgrp << 2, kg = l >> 3;
    const float* cxw = cxs + w * KD;
    float4 acc = {0,0,0,0};
    #pragma unroll
    for (int j = 0; j < 16; ++j) {
        const int k = (j << 3) + kg;
        const float* wr = w_s + k * WSTR + d0;   // banks (k+d0..d0+3)%32: 2-way = free
        const float cv = cxw[k];                 // 8 addrs -> 8 banks, broadcast
        acc.x += cv * wr[0]; acc.y += cv * wr[1]; acc.z += cv * wr[2]; acc.w += cv * wr[3];
    }
    #pragma unroll
    for (int off = 8; off < 64; off <<= 1) {     // reduce over kg lanes
        acc.x += __shfl_xor(acc.x, off, 64);
        acc.y += __shfl_xor(acc.y, off, 64);
        acc.z += __shfl_xor(acc.z, off, 64);
        acc.w += __shfl_xor(acc.w, off, 64);
    }
    // 3) squash: sn = sum_d s^2 (reduce over the 8 dgrp lanes)
    float ss = acc.x*acc.x + acc.y*acc.y + acc.z*acc.z + acc.w*acc.w;
    #pragma unroll
    for (int off = 1; off < 8; off <<= 1) ss += __shfl_xor(ss, off, 64);
    const float scale = ss / ((1.f + ss) * (sqrtf(ss) + 1e-8f));
    float4 v4; v4.x = acc.x*scale; v4.y = acc.y*scale; v4.z = acc.z*scale; v4.w = acc.w*scale;

    if (final_) {
        if (kg == 0) *(float4*)(out_g + ((size_t)(b * NC) + pb_n) * DC + d0) = v4;
    } else {
        // 4) wv[k] = sum_d W[k][d] * v[d]; lane owns k = l and l+64
        float* vbw = vb + w * DC;
        if (kg == 0) *(float4*)(vbw + d0) = v4;
        __syncthreads();
        float wv0 = 0.f, wv1 = 0.f;
        #pragma unroll
        for (int j = 0; j < 8; ++j) {
            const float4 vv = *(const float4*)(vbw + (j << 2));     // same addr: broadcast
            const float* wa = w_s + l * WSTR + (j << 2);            // bank (l+4j+c)%32: 2-way
            const float* wb = w_s + (l + 64) * WSTR + (j << 2);
            wv0 += wa[0]*vv.x + wa[1]*vv.y + wa[2]*vv.z + wa[3]*vv.w;
            wv1 += wb[0]*vv.x + wb[1]*vv.y + wb[2]*vv.z + wb[3]*vv.w;
        }
        float* wrow = wv_g + ((size_t)(b * NC) + pb_n) * KD;
        wrow[l] = wv0; wrow[l + 64] = wv1;   // coalesced 256B x2 per wave
    }
}

extern "C" void kernel_launch(void* const* d_in, const int* in_sizes, int n_in,
                              void* d_out, int out_size, void* d_ws, size_t ws_size,
                              hipStream_t stream) {
    const float* x  = (const float*)d_in[0];
    const float* W  = (const float*)d_in[1];
    const float* b0 = (const float*)d_in[2];
    float* out = (float*)d_out;

    float* cxp   = (float*)d_ws;                 // 8 MB
    float* wv    = cxp + CXP_SZ;                 // 1 MB
    float* bb_ws = wv + WV_SZ;                   // 4 MB

    // iter 0: softmax(b0) + cx
    kA<<<NBLK, NTHR, 0, stream>>>(b0, x, nullptr, nullptr, cxp, 0, 0);
    kB<<<NBLK, NTHR, 0, stream>>>(cxp, W, wv, nullptr, 0);
    // iter 1: uv+bb (persist) + softmax + cx
    kA<<<NBLK, NTHR, 0, stream>>>(b0, x, wv, bb_ws, cxp, 1, 1);
    kB<<<NBLK, NTHR, 0, stream>>>(cxp, W, wv, nullptr, 0);
    // iter 2: uv+bb + softmax + cx (bb not persisted)
    kA<<<NBLK, NTHR, 0, stream>>>(bb_ws, x, wv, nullptr, cxp, 1, 0);
    kB<<<NBLK, NTHR, 0, stream>>>(cxp, W, nullptr, out, 1);
}